// Round 1
// 1111.055 us; speedup vs baseline: 1.0326x; 1.0326x over previous
//
#include <hip/hip_runtime.h>
#include <cstdint>
#include <cstddef>

// Problem constants: B=32, L=2048, D=1024, E=2048
#define B_ 32
#define L_ 2048
#define D_ 1024
#define E_ 2048
// GEMM view: M = B*L = 65536 rows (b,l), N = D = 1024, K = E = 2048

typedef __attribute__((ext_vector_type(8))) short short8;
typedef __attribute__((ext_vector_type(16))) float f32x16;
typedef __attribute__((ext_vector_type(4))) unsigned int uint4v;

// ---- async global->LDS, 16B per lane; LDS dest = uniform base + lane*16 ----
__device__ __forceinline__ void async_copy16(const void* g, void* l) {
  __builtin_amdgcn_global_load_lds((const __attribute__((address_space(1))) void*)g,
                                   (__attribute__((address_space(3))) void*)l, 16, 0, 0);
}

// pack two fp32 -> bf16x2 (round-half-up: add 0x8000, take hi16)
__device__ __forceinline__ unsigned int pack_bf16_2(float lo, float hi) {
  unsigned int ul = __builtin_bit_cast(unsigned int, lo) + 0x8000u;
  unsigned int uh = __builtin_bit_cast(unsigned int, hi) + 0x8000u;
  return (ul >> 16) | (uh & 0xFFFF0000u);
}

__device__ __forceinline__ float fast_tanh(float x) {
  float e = __expf(2.0f * x);
  return 1.0f - 2.0f / (e + 1.0f);
}

// ---------------- kernel 1: s[b][i] = sum_d dec[b][d] * Ws[i][d] ------------
__global__ __launch_bounds__(256) void k_s(const float* __restrict__ dec,
                                           const float* __restrict__ Ws,
                                           float* __restrict__ s) {
  int wid = threadIdx.x >> 6, lane = threadIdx.x & 63;
  int out = blockIdx.x * 4 + wid;            // 0..32767
  int b = out >> 10, i = out & 1023;
  const float* dr = dec + b * D_;
  const float* wr = Ws + (size_t)i * D_;
  float acc = 0.f;
#pragma unroll
  for (int c = 0; c < 4; ++c) {
    int d0 = c * 256 + lane * 4;
    float4 x = *(const float4*)(dr + d0);
    float4 w = *(const float4*)(wr + d0);
    acc += x.x * w.x + x.y * w.y + x.z * w.z + x.w * w.w;
  }
#pragma unroll
  for (int off = 32; off >= 1; off >>= 1) acc += __shfl_xor(acc, off, 64);
  if (lane == 0) s[out] = acc;
}

// ---------------- kernel 2: W_h fp32 -> bf16 (2M elements) ------------------
__global__ __launch_bounds__(256) void k_cvt(const float* __restrict__ src,
                                             unsigned short* __restrict__ dst) {
  size_t i = ((size_t)blockIdx.x * 256 + threadIdx.x) * 8;
  float4 a = *(const float4*)(src + i);
  float4 b = *(const float4*)(src + i + 4);
  uint4v p;
  p.x = pack_bf16_2(a.x, a.y);
  p.y = pack_bf16_2(a.z, a.w);
  p.z = pack_bf16_2(b.x, b.y);
  p.w = pack_bf16_2(b.z, b.w);
  *(uint4v*)(dst + i) = p;
}

// ---------------- kernel 3: fused GEMM + tanh + v-dot -----------------------
// scores[m] = sum_n v[n] * tanh(s[b][n] + sum_k enc[m][k]*Whb[n][k]),  m=(b,l)
// Block tile 128(M)x128(N), BK=64; 256 threads = 4 waves (2M x 2N), each wave
// owns a 64x64 output tile = 2x2 frags of MFMA 32x32x16 bf16.
// A (enc) stays fp32 in LDS (256-B rows = 16x 16B units, xor-swizzled by
// r&15 -> conflict-free per 8-lane phase); packed to bf16 at fragment read.
// B (whb bf16): 64 lines x 256 B, 2 n-rows/line, units xor-swizzled by
// line&15 (2-way on read = free).
// Structure: m97-class 2-barrier K-loop, 3 blocks/CU (48 KB LDS).
__global__ __launch_bounds__(256, 3) void k_gemm(const float* __restrict__ enc,
                                                 const unsigned short* __restrict__ whb,
                                                 const float* __restrict__ sbias,
                                                 const float* __restrict__ vvec,
                                                 float* __restrict__ scores) {
  __shared__ alignas(16) float As[128 * 64];          // 32 KB fp32
  __shared__ alignas(16) unsigned short Bs[64 * 128]; // 16 KB bf16 (64 lines x 256 B)

  const int tid = threadIdx.x;
  const int wid = tid >> 6;        // 0..3
  const int lane = tid & 63;
  const int wm = wid >> 1;         // wave row (M)
  const int wn = wid & 1;          // wave col (N)

  // XCD swizzle: all 8 N-tiles of one M-tile share flat%8 -> same XCD L2.
  const int flat = blockIdx.x;
  const int nt = (flat >> 3) & 7;
  const int mt = (flat & 7) | ((flat >> 6) << 3);
  const int m_base = mt * 128, n_base = nt * 128;
  const int b_idx = m_base >> 11;  // 128 | 2048 -> b uniform per block

  // --- staging source addressing (global address carries the LDS swizzle) ---
  const int rp = lane >> 4;        // row/line within 4-chunk
  const int ul = lane & 15;        // stored 16B unit
  const int u0 = ul ^ rp;
  // A chunk it: rows wid*32 + it*4 + rp, fetch unit = u0 ^ ((it&3)<<2)
  const float* gA = enc + (size_t)(m_base + wid * 32 + rp) * E_;
  int offA[8];
#pragma unroll
  for (int it = 0; it < 8; ++it)
    offA[it] = it * 4 * E_ + ((u0 ^ ((it & 3) << 2)) << 2);
  // B chunk it: line = wid*16 + it*4 + rp; ulog = u0 ^ (it<<2);
  //   n = 2*line + (ulog>>3); k-off (shorts) = (ulog&7)*8
  const unsigned short* gB = whb + (size_t)n_base * E_;
  int offB[4];
#pragma unroll
  for (int it = 0; it < 4; ++it) {
    int ulog = u0 ^ (it << 2);
    offB[it] = (wid * 32 + it * 8 + 2 * rp + (ulog >> 3)) * E_ + (ulog & 7) * 8;
  }

  // --- fragment read addressing (loop-invariant, swizzled) ---
  const int col = lane & 31;
  const int h = lane >> 5;
  const float* arow[2];
#pragma unroll
  for (int mi = 0; mi < 2; ++mi) arow[mi] = &As[(wm * 64 + mi * 32 + col) * 64];
  int aoff[4][2];
#pragma unroll
  for (int ks = 0; ks < 4; ++ks)
#pragma unroll
    for (int j = 0; j < 2; ++j)
      aoff[ks][j] = ((ks * 4 + h * 2 + j) ^ (col & 15)) * 4;   // floats
  const unsigned short* brow[2];
#pragma unroll
  for (int ni = 0; ni < 2; ++ni) brow[ni] = &Bs[(wn * 32 + ni * 16 + (col >> 1)) * 128];
  int boff[4];
#pragma unroll
  for (int ks = 0; ks < 4; ++ks)
    boff[ks] = ((((col & 1) << 3) + ks * 2 + h) ^ ((col >> 1) & 15)) * 8;  // shorts

  f32x16 acc[2][2] = {};

  for (int kk = 0; kk < E_; kk += 64) {
    __syncthreads();  // previous iteration's LDS reads done
#pragma unroll
    for (int it = 0; it < 8; ++it)
      async_copy16(gA + offA[it] + kk, &As[(wid * 32 + it * 4) * 64]);
#pragma unroll
    for (int it = 0; it < 4; ++it)
      async_copy16(gB + offB[it] + kk, &Bs[(wid * 16 + it * 4) * 128]);
    __syncthreads();  // compiler drains vmcnt(0) before barrier -> LDS ready

#pragma unroll
    for (int ks = 0; ks < 4; ++ks) {
      short8 bf[2];
#pragma unroll
      for (int ni = 0; ni < 2; ++ni) bf[ni] = *(const short8*)(brow[ni] + boff[ks]);
#pragma unroll
      for (int mi = 0; mi < 2; ++mi) {
        float4 f0 = *(const float4*)(arow[mi] + aoff[ks][0]);
        float4 f1 = *(const float4*)(arow[mi] + aoff[ks][1]);
        uint4v pa;
        pa.x = pack_bf16_2(f0.x, f0.y);
        pa.y = pack_bf16_2(f0.z, f0.w);
        pa.z = pack_bf16_2(f1.x, f1.y);
        pa.w = pack_bf16_2(f1.z, f1.w);
        short8 af = __builtin_bit_cast(short8, pa);
#pragma unroll
        for (int ni = 0; ni < 2; ++ni)
          acc[mi][ni] = __builtin_amdgcn_mfma_f32_32x32x16_bf16(af, bf[ni], acc[mi][ni], 0, 0, 0);
      }
    }
  }

  // --- epilogue: partial = sum over this wave's 64 n of v[n]*tanh(s+h) ---
  // 32x32 C/D layout (m74/m101): col = lane&31, row = (reg&3)+8*(reg>>2)+4*(lane>>5)
  float vv[2], sv[2];
#pragma unroll
  for (int ni = 0; ni < 2; ++ni) {
    int n = n_base + wn * 64 + ni * 32 + col;
    vv[ni] = vvec[n];
    sv[ni] = sbias[b_idx * D_ + n];
  }
#pragma unroll
  for (int mi = 0; mi < 2; ++mi) {
#pragma unroll
    for (int reg = 0; reg < 16; ++reg) {
      float sum = 0.f;
#pragma unroll
      for (int ni = 0; ni < 2; ++ni)
        sum += vv[ni] * fast_tanh(sv[ni] + acc[mi][ni][reg]);
      sum += __shfl_xor(sum, 1, 64);
      sum += __shfl_xor(sum, 2, 64);
      sum += __shfl_xor(sum, 4, 64);
      sum += __shfl_xor(sum, 8, 64);
      sum += __shfl_xor(sum, 16, 64);
      if (col == 0)
        atomicAdd(&scores[m_base + wm * 64 + mi * 32 + (reg & 3) + 8 * (reg >> 2) + h * 4], sum);
    }
  }
}

// ---------------- kernel 4: softmax over L per b (in-place) -----------------
__global__ __launch_bounds__(256) void k_softmax(float* __restrict__ sc) {
  int b = blockIdx.x, tid = threadIdx.x;
  int lane = tid & 63, wid = tid >> 6;
  float* row = sc + (size_t)b * L_;
  float vals[8];
  float mx = -1e30f;
#pragma unroll
  for (int j = 0; j < 8; ++j) { vals[j] = row[tid + j * 256]; mx = fmaxf(mx, vals[j]); }
#pragma unroll
  for (int off = 32; off >= 1; off >>= 1) mx = fmaxf(mx, __shfl_xor(mx, off, 64));
  __shared__ float redm[4], reds[4];
  if (lane == 0) redm[wid] = mx;
  __syncthreads();
  mx = fmaxf(fmaxf(redm[0], redm[1]), fmaxf(redm[2], redm[3]));
  float sum = 0.f;
#pragma unroll
  for (int j = 0; j < 8; ++j) { vals[j] = __expf(vals[j] - mx); sum += vals[j]; }
#pragma unroll
  for (int off = 32; off >= 1; off >>= 1) sum += __shfl_xor(sum, off, 64);
  if (lane == 0) reds[wid] = sum;
  __syncthreads();
  sum = reds[0] + reds[1] + reds[2] + reds[3];
  float inv = 1.0f / sum;
#pragma unroll
  for (int j = 0; j < 8; ++j) row[tid + j * 256] = vals[j] * inv;
}

// ---------------- kernel 5: ctx[b][e] = sum_l attn[b][l] * enc[b][l][e] -----
// Occupancy fix: 2048 blocks (was 512 = 2/CU, latency-bound ~1 TB/s).
// grid.x = 64: lc = bx>>1 (32 chunks of 64 rows), eh = bx&1 (E halves).
// 256 threads x float4 cover one 1024-col E-half; 8 blocks/CU, full TLP.
__global__ __launch_bounds__(256) void k_ctx(const float* __restrict__ enc,
                                             const float* __restrict__ attn,
                                             float* __restrict__ ctx) {
  int b = blockIdx.y;
  int lc = blockIdx.x >> 1;        // 0..31, 64 rows each
  int eh = blockIdx.x & 1;         // E half
  int t = threadIdx.x;
  __shared__ float aw[64];
  if (t < 64) aw[t] = attn[(size_t)b * L_ + lc * 64 + t];
  __syncthreads();
  const float* base = enc + ((size_t)b * L_ + (size_t)lc * 64) * E_ + eh * 1024;
  float4 a0 = make_float4(0.f, 0.f, 0.f, 0.f);
#pragma unroll 4
  for (int l = 0; l < 64; ++l) {
    float w = aw[l];
    float4 x0 = *(const float4*)(base + (size_t)l * E_ + t * 4);
    a0.x += w * x0.x; a0.y += w * x0.y; a0.z += w * x0.z; a0.w += w * x0.w;
  }
  float* cb = ctx + (size_t)b * E_ + eh * 1024 + t * 4;
  atomicAdd(cb + 0, a0.x);
  atomicAdd(cb + 1, a0.y);
  atomicAdd(cb + 2, a0.z);
  atomicAdd(cb + 3, a0.w);
}

extern "C" void kernel_launch(void* const* d_in, const int* in_sizes, int n_in,
                              void* d_out, int out_size, void* d_ws, size_t ws_size,
                              hipStream_t stream) {
  const float* dec = (const float*)d_in[0];  // [32,1024]
  const float* enc = (const float*)d_in[1];  // [32,2048,2048]
  const float* Ws  = (const float*)d_in[2];  // [1024,1024]
  const float* Wh  = (const float*)d_in[3];  // [1024,2048]
  const float* v   = (const float*)d_in[4];  // [1024]

  float* ctx  = (float*)d_out;                   // [32,2048]
  float* attn = (float*)d_out + B_ * E_;         // [32,2048]; also scores scratch

  // workspace: W_h in bf16 (4 MB) + s (128 KB)
  unsigned short* whb = (unsigned short*)d_ws;
  float* sbuf = (float*)((char*)d_ws + (size_t)D_ * E_ * sizeof(unsigned short));

  // zero ctx + scores (both accumulated via atomics)
  hipMemsetAsync(d_out, 0, (size_t)out_size * sizeof(float), stream);

  k_s<<<dim3((B_ * D_) / 4), dim3(256), 0, stream>>>(dec, Ws, sbuf);
  k_cvt<<<dim3((D_ * E_) / (256 * 8)), dim3(256), 0, stream>>>(Wh, whb);
  k_gemm<<<dim3((B_ * L_ / 128) * (D_ / 128)), dim3(256), 0, stream>>>(enc, whb, sbuf, v, attn);
  k_softmax<<<dim3(B_), dim3(256), 0, stream>>>(attn);
  k_ctx<<<dim3(64, B_), dim3(256), 0, stream>>>(enc, attn, ctx);
}